// Round 5
// baseline (3018.678 us; speedup 1.0000x reference)
//
#include <hip/hip_runtime.h>
#include <stdint.h>

#define T_DIM 512
#define B_DIM 256
#define OBS_DIM 128
#define H_DIM 256
#define A_DIM 32
#define TB (T_DIM*B_DIM)   // 131072

typedef unsigned short u16;
typedef unsigned int   u32;
typedef _Float16 half2v __attribute__((ext_vector_type(2)));
typedef __attribute__((ext_vector_type(8))) short short8;   // 8 bf16 (4 VGPRs)
typedef __attribute__((ext_vector_type(4))) float f32x4;

__device__ __forceinline__ float bf2f(u16 v){ return __uint_as_float(((u32)v)<<16); }
__device__ __forceinline__ u16 f2bf(float f){
    u32 x = __float_as_uint(f);
    u32 r = x + 0x7fffu + ((x>>16)&1u);   // round-to-nearest-even
    return (u16)(r>>16);
}
__device__ __forceinline__ float2 bfpair(u32 u){
    return make_float2(__uint_as_float(u<<16), __uint_as_float(u & 0xffff0000u));
}

// packed-f16-pair dot: acc += a.lo*b.lo + a.hi*b.hi
__device__ __forceinline__ float dot2(u32 a, u32 b, float c){
#if __has_builtin(__builtin_amdgcn_fdot2)
    return __builtin_amdgcn_fdot2(__builtin_bit_cast(half2v,a),
                                  __builtin_bit_cast(half2v,b), c, false);
#else
    half2v ha = __builtin_bit_cast(half2v,a), hb = __builtin_bit_cast(half2v,b);
    return fmaf((float)ha[0],(float)hb[0], fmaf((float)ha[1],(float)hb[1], c));
#endif
}

// ---------------------------------------------------------------------------
// dones dtype probe (u8 bool vs i32 vs f32) via nonzero byte positions mod 4.
// ---------------------------------------------------------------------------
__global__ void zero_flags_kernel(int* p){ if(threadIdx.x<4) p[threadIdx.x]=0; }

__global__ void detect_kernel(const unsigned char* __restrict__ d, int n, int* __restrict__ flags){
    int f=0;
    for(int p = blockIdx.x*blockDim.x+threadIdx.x; p<n; p += gridDim.x*blockDim.x){
        if(d[p]){ int m=p&3; if(m==1) f|=1; else if(m>=2) f|=2; }
    }
    if(f) atomicOr(flags, f);
}

// ---------------------------------------------------------------------------
// Recurrent weights -> packed f16 pairs: dst[((m*32+q)*256 + j)*4 + e] packs
// k=2*(4q+e), 2*(4q+e)+1 of column j of matrix m.
// ---------------------------------------------------------------------------
__global__ void cvt_wt_kernel(const float* __restrict__ Whr, const float* __restrict__ Whz,
                              const float* __restrict__ Whn, u32* __restrict__ dst){
    int i = blockIdx.x*blockDim.x + threadIdx.x;
    if(i >= 3*32*256*4) return;
    int e = i & 3;
    int j = (i >> 2) & 255;
    int q = (i >> 10) & 31;
    int m = i >> 15;
    const float* W = (m==0) ? Whr : (m==1) ? Whz : Whn;
    int kp = q*4 + e, k = 2*kp;
    _Float16 lo = (_Float16)W[(size_t)k    *H_DIM + j];
    _Float16 hi = (_Float16)W[(size_t)(k+1)*H_DIM + j];
    dst[i] = (u32)__builtin_bit_cast(u16,lo) | ((u32)__builtin_bit_cast(u16,hi) << 16);
}

// GEMM weight f32 [K][N] -> bf16 transposed [N][K]
__global__ void cvt_wT_kernel(const float* __restrict__ W, u16* __restrict__ dst,
                              int K, int N){
    int i = blockIdx.x*blockDim.x + threadIdx.x;
    if(i >= K*N) return;
    int n = i / K;
    int k = i - n*K;
    dst[i] = f2bf(W[(size_t)k*N + n]);
}

// ---------------------------------------------------------------------------
// f32 GEMM (emb only): C[M,N](bf16) = relu(A_f32[M,K] @ W[K,N] + bias)
// ---------------------------------------------------------------------------
__global__ __launch_bounds__(256)
void gemm_f32_kernel(const float* __restrict__ A, const float* __restrict__ W,
                     const float* __restrict__ bias, u16* __restrict__ C,
                     int M, int N, int K)
{
    __shared__ float As[16][128];
    __shared__ float Ws[16][128];
    const int tid = threadIdx.x;
    const int tr = tid>>4, tc = tid&15;
    const int lar = tid>>1, lac = (tid&1)*8;
    const int lwr = tid>>4, lwc = (tid&15)*8;
    const int rowBase = blockIdx.y*128;
    const int colBase = blockIdx.x*128;

    float acc[8][8];
    #pragma unroll
    for(int i=0;i<8;i++){
        #pragma unroll
        for(int j=0;j<8;j++) acc[i][j]=0.f;
    }

    for(int kb=0; kb<K; kb+=16){
        {
            const float4* p = (const float4*)(A + (size_t)(rowBase+lar)*K + kb + lac);
            float4 a0=p[0], a1=p[1];
            As[lac+0][lar]=a0.x; As[lac+1][lar]=a0.y; As[lac+2][lar]=a0.z; As[lac+3][lar]=a0.w;
            As[lac+4][lar]=a1.x; As[lac+5][lar]=a1.y; As[lac+6][lar]=a1.z; As[lac+7][lar]=a1.w;
        }
        {
            const float4* p = (const float4*)(W + (size_t)(kb+lwr)*N + colBase + lwc);
            float4 w0 = p[0], w1 = p[1];
            *(float4*)&Ws[lwr][lwc]   = w0;
            *(float4*)&Ws[lwr][lwc+4] = w1;
        }
        __syncthreads();
        #pragma unroll
        for(int kk=0;kk<16;kk++){
            float4 a0 = *(const float4*)&As[kk][tr*8];
            float4 a1 = *(const float4*)&As[kk][tr*8+4];
            float4 w0 = *(const float4*)&Ws[kk][tc*8];
            float4 w1 = *(const float4*)&Ws[kk][tc*8+4];
            float av[8]={a0.x,a0.y,a0.z,a0.w,a1.x,a1.y,a1.z,a1.w};
            float wv[8]={w0.x,w0.y,w0.z,w0.w,w1.x,w1.y,w1.z,w1.w};
            #pragma unroll
            for(int i=0;i<8;i++){
                #pragma unroll
                for(int j=0;j<8;j++) acc[i][j] = fmaf(av[i], wv[j], acc[i][j]);
            }
        }
        __syncthreads();
    }

    float bv[8];
    #pragma unroll
    for(int j=0;j<8;j++) bv[j] = bias[colBase + tc*8 + j];
    #pragma unroll
    for(int i=0;i<8;i++){
        u16 h[8];
        #pragma unroll
        for(int j=0;j<8;j++){
            float v = fmaxf(acc[i][j] + bv[j], 0.f);
            h[j] = f2bf(v);
        }
        *(uint4*)(C + (size_t)(rowBase + tr*8 + i)*N + colBase + tc*8) = *(uint4*)h;
    }
}

// ---------------------------------------------------------------------------
// MFMA bf16 GEMM: C[M,N](bf16) = opt_relu(A_bf16[M,K] @ Bt^T + bias), where
// Bt is the weight pre-transposed to bf16 [N][K]. 128x128 tile, BK=32,
// 256 threads = 4 waves in 2x2, each wave 64x64 via 16x mfma_f32_16x16x32_bf16.
// Verified layouts: A/B frag [idx=lane&15][k=quad*8+j]; C/D col=lane&15,
// row=quad*4+reg.
// ---------------------------------------------------------------------------
template<int RELU>
__global__ __launch_bounds__(256, 2)
void gemm_mfma_kernel(const u16* __restrict__ A, const u16* __restrict__ Bt,
                      const float* __restrict__ bias, u16* __restrict__ C,
                      int M, int N, int K)
{
    __shared__ u16 As[128*32];
    __shared__ u16 Bs[128*32];
    const int tid  = threadIdx.x;
    const int wave = tid >> 6;
    const int lane = tid & 63;
    const int ln15 = lane & 15;
    const int quad = lane >> 4;
    const int wm = wave & 1, wn = wave >> 1;
    const int rowBase = blockIdx.y*128;
    const int colBase = blockIdx.x*128;

    f32x4 acc[4][4] = {};   // [mt][nt], 4 f32 each

    const int sr = tid >> 1;          // staging row 0..127
    const int sc = (tid & 1) * 16;    // staging col 0 or 16 (of 32)

    for(int kb = 0; kb < K; kb += 32){
        const u16* ag = A  + (size_t)(rowBase+sr)*K + kb + sc;
        const u16* bg = Bt + (size_t)(colBase+sr)*K + kb + sc;
        uint4 av0 = *(const uint4*)ag;
        uint4 av1 = *(const uint4*)(ag+8);
        uint4 bv0 = *(const uint4*)bg;
        uint4 bv1 = *(const uint4*)(bg+8);
        *(uint4*)&As[sr*32 + sc]     = av0;
        *(uint4*)&As[sr*32 + sc + 8] = av1;
        *(uint4*)&Bs[sr*32 + sc]     = bv0;
        *(uint4*)&Bs[sr*32 + sc + 8] = bv1;
        __syncthreads();

        short8 af[4], bf[4];
        #pragma unroll
        for(int mt=0;mt<4;mt++)
            af[mt] = *(const short8*)&As[(wm*64+mt*16+ln15)*32 + quad*8];
        #pragma unroll
        for(int nt=0;nt<4;nt++)
            bf[nt] = *(const short8*)&Bs[(wn*64+nt*16+ln15)*32 + quad*8];
        #pragma unroll
        for(int mt=0;mt<4;mt++){
            #pragma unroll
            for(int nt=0;nt<4;nt++){
                acc[mt][nt] = __builtin_amdgcn_mfma_f32_16x16x32_bf16(
                                  af[mt], bf[nt], acc[mt][nt], 0, 0, 0);
            }
        }
        __syncthreads();
    }

    #pragma unroll
    for(int nt=0;nt<4;nt++){
        int n = colBase + wn*64 + nt*16 + ln15;
        float bv = bias[n];
        #pragma unroll
        for(int mt=0;mt<4;mt++){
            #pragma unroll
            for(int r=0;r<4;r++){
                int m = rowBase + wm*64 + mt*16 + quad*4 + r;
                float v = acc[mt][nt][r] + bv;
                if(RELU) v = fmaxf(v, 0.f);
                C[(size_t)m*N + n] = f2bf(v);
            }
        }
    }
}

// ---------------------------------------------------------------------------
// GRU scan: 64 blocks (4 batch rows each) x 768 threads. Thread (m=tid>>8,
// j=tid&255) owns column j of matrix m as 32 register uint4 of packed f16
// pairs, reused across the 4 rows (4x less weight traffic than R4). h kept
// as packed f16 in LDS, broadcast uint4 reads. Gate inputs prefetched per
// thread ((m,j) x 4 rows covers gi's 3*256 layout exactly).
// ---------------------------------------------------------------------------
__global__ __launch_bounds__(768, 3)
void scan_kernel(const u16* __restrict__ gi, const void* __restrict__ dones,
                 const int* __restrict__ flags, const uint4* __restrict__ Wt4,
                 const float* __restrict__ bhn, float* __restrict__ h_carry,
                 u16* __restrict__ y, int t0, int Tc)
{
    __shared__ __align__(16) u32 hbuf[2][4][128];   // packed f16 h, double-buffered
    __shared__ float accb[3][4][256];
    __shared__ float gib[3][4][256];
    __shared__ int dnb[4];
    const int tid = threadIdx.x;
    const int j   = tid & 255;
    const int m   = tid >> 8;          // 0..2
    const int b0  = blockIdx.x*4;
    const int fl  = flags[0];
    const int mode = (fl&1) ? 0 : ((fl&2) ? 2 : 1);  // 0=u8, 1=i32, 2=f32

    auto getdone = [&](int t, int row)->bool{
        int idx = t*B_DIM + row;
        if(mode==0) return ((const unsigned char*)dones)[idx] != 0;
        if(mode==1) return ((const int*)dones)[idx] != 0;
        return ((const float*)dones)[idx] != 0.f;
    };

    // weight column (m, j): 32 uint4 = 128 packed f16 pairs
    uint4 w[32];
    #pragma unroll
    for(int q=0;q<32;q++) w[q] = Wt4[(size_t)(m*32+q)*256 + j];

    const float bh = bhn[j];

    for(int idx=tid; idx<1024; idx+=768){
        int g = idx>>8;
        bool d0 = getdone(t0, b0+g);
        float ho = d0 ? 0.f : h_carry[(size_t)(b0+g)*H_DIM + j];
        ((_Float16*)hbuf[0][g])[j] = (_Float16)ho;
    }
    __syncthreads();

    int cur = 0;
    for(int t=0; t<Tc; ++t){
        // prefetch gate inputs for this thread's (m,j) across 4 rows
        u16 giv[4];
        #pragma unroll
        for(int g=0; g<4; ++g)
            giv[g] = gi[((size_t)t*B_DIM + b0+g)*768 + m*256 + j];
        if(tid < 4)
            dnb[tid] = (t < Tc-1) ? (getdone(t0+t+1, b0+tid) ? 1 : 0) : 0;

        // dot: acc[g] = sum_k h[g][k] * Wm[k][j], 2 chains per row
        float accA[4] = {0.f,0.f,0.f,0.f};
        float accB[4] = {0.f,0.f,0.f,0.f};
        #pragma unroll
        for(int q=0;q<32;q++){
            uint4 wq = w[q];
            #pragma unroll
            for(int g=0; g<4; ++g){
                uint4 hv = ((const uint4*)hbuf[cur][g])[q];
                accA[g] = dot2(wq.x, hv.x, accA[g]);
                accB[g] = dot2(wq.y, hv.y, accB[g]);
                accA[g] = dot2(wq.z, hv.z, accA[g]);
                accB[g] = dot2(wq.w, hv.w, accB[g]);
            }
        }
        #pragma unroll
        for(int g=0; g<4; ++g){
            accb[m][g][j] = accA[g] + accB[g];
            gib[m][g][j]  = bf2f(giv[g]);
        }
        __syncthreads();

        // gate: 1024 items (g,j); jj == j for both assignments since 768%256==0
        for(int idx=tid; idx<1024; idx+=768){
            int g = idx>>8;
            float ir  = gib[0][g][j];
            float iz  = gib[1][g][j];
            float inn = gib[2][g][j];
            float r = 1.f/(1.f + __expf(-(ir + accb[0][g][j])));
            float z = 1.f/(1.f + __expf(-(iz + accb[1][g][j])));
            float x = inn + r*(accb[2][g][j] + bh);
            float e2 = __expf(2.f*x);
            float n = 1.f - 2.f/(e2 + 1.f);        // tanh(x)
            float ho = (float)((const _Float16*)hbuf[cur][g])[j];
            float hn = (1.f - z)*n + z*ho;
            y[((size_t)t*B_DIM + b0+g)*H_DIM + j] = f2bf(hn);
            float hkeep = dnb[g] ? 0.f : hn;       // dn=0 on chunk's last step
            ((_Float16*)hbuf[cur^1][g])[j] = (_Float16)hkeep;
        }
        __syncthreads();
        cur ^= 1;
    }

    for(int idx=tid; idx<1024; idx+=768){
        int g = idx>>8;
        h_carry[(size_t)(b0+g)*H_DIM + j] = (float)((const _Float16*)hbuf[cur][g])[j];
    }
}

// ---------------------------------------------------------------------------
// Actor head stage 2: logits[rows,32] = ah[rows,256] @ W_a2 + b_a2 - (1-avail)*1e10
// ---------------------------------------------------------------------------
__global__ __launch_bounds__(256)
void actor2_kernel(const u16* __restrict__ ah, const float* __restrict__ W_a2,
                   const float* __restrict__ b_a2, const float* __restrict__ avail,
                   float* __restrict__ logits)
{
    __shared__ u16 ahs[64][264];
    const int tid = threadIdx.x;
    const int r0 = blockIdx.x*64;
    {
        int row = tid & 63;
        int c0 = (tid >> 6) * 64;
        const uint4* gp = (const uint4*)(ah + (size_t)(r0+row)*H_DIM + c0);
        #pragma unroll
        for(int q=0;q<8;q++){
            uint4 u = gp[q];
            u32* dst = (u32*)&ahs[row][c0 + q*8];
            dst[0]=u.x; dst[1]=u.y; dst[2]=u.z; dst[3]=u.w;
        }
    }
    __syncthreads();
    const int c  = tid & 31;
    const int rg = tid >> 5;   // 0..7
    float acc[8]={0.f,0.f,0.f,0.f,0.f,0.f,0.f,0.f};
    float bc = b_a2[c];
    for(int k=0;k<H_DIM;k+=4){
        float w0 = W_a2[(k+0)*A_DIM + c];
        float w1 = W_a2[(k+1)*A_DIM + c];
        float w2 = W_a2[(k+2)*A_DIM + c];
        float w3 = W_a2[(k+3)*A_DIM + c];
        #pragma unroll
        for(int rr=0;rr<8;rr++){
            uint2 av = *(const uint2*)&ahs[rg*8+rr][k];
            float2 p0 = bfpair(av.x), p1 = bfpair(av.y);
            acc[rr] = fmaf(p0.x,w0,fmaf(p0.y,w1,fmaf(p1.x,w2,fmaf(p1.y,w3,acc[rr]))));
        }
    }
    #pragma unroll
    for(int rr=0;rr<8;rr++){
        int grow = r0 + rg*8 + rr;
        float av = avail[(size_t)grow*A_DIM + c];
        logits[(size_t)grow*A_DIM + c] = acc[rr] + bc - (1.f-av)*1e10f;
    }
}

// ---------------------------------------------------------------------------
// Critic head stage 2: value[row] = ch[row,256] @ W_c2 + b_c2. Wave per row.
// ---------------------------------------------------------------------------
__global__ __launch_bounds__(256)
void critic2_kernel(const u16* __restrict__ ch, const float* __restrict__ W_c2,
                    const float* __restrict__ b_c2, float* __restrict__ value)
{
    const int lane = threadIdx.x & 63;
    const int wid  = threadIdx.x >> 6;
    const int row  = blockIdx.x*4 + wid;
    uint2 av = *(const uint2*)(ch + (size_t)row*H_DIM + lane*4);
    float2 p0 = bfpair(av.x), p1 = bfpair(av.y);
    float4 wv = *(const float4*)(W_c2 + lane*4);
    float acc = p0.x*wv.x + p0.y*wv.y + p1.x*wv.z + p1.y*wv.w;
    #pragma unroll
    for(int off=32; off>0; off>>=1) acc += __shfl_down(acc, off, 64);
    if(lane==0) value[row] = acc + b_c2[0];
}

// ---------------------------------------------------------------------------
extern "C" void kernel_launch(void* const* d_in, const int* in_sizes, int n_in,
                              void* d_out, int out_size, void* d_ws, size_t ws_size,
                              hipStream_t stream)
{
    const float* hidden = (const float*)d_in[0];
    const float* obs    = (const float*)d_in[1];
    const void*  dones  = d_in[2];
    const float* avail  = (const float*)d_in[3];
    const float* W_emb  = (const float*)d_in[4];
    const float* b_emb  = (const float*)d_in[5];
    const float* Wi     = (const float*)d_in[6];
    const float* bi     = (const float*)d_in[7];
    const float* Whr    = (const float*)d_in[8];
    const float* Whz    = (const float*)d_in[9];
    const float* Whn    = (const float*)d_in[10];
    const float* bhn    = (const float*)d_in[11];
    const float* W_a1   = (const float*)d_in[12];
    const float* b_a1   = (const float*)d_in[13];
    const float* W_a2   = (const float*)d_in[14];
    const float* b_a2   = (const float*)d_in[15];
    const float* W_c1   = (const float*)d_in[16];
    const float* b_c1   = (const float*)d_in[17];
    const float* W_c2   = (const float*)d_in[18];
    const float* b_c2   = (const float*)d_in[19];

    float* out_hidden = (float*)d_out;                       // 65536
    float* out_logits = out_hidden + (size_t)B_DIM*H_DIM;    // 4194304
    float* out_value  = out_logits + (size_t)TB*A_DIM;       // 131072

    // ---- workspace layout (chunk size adapted to ws_size, deterministic) ----
    // fixed: wt(scan) + wiT + wa1T + wc1T + h_carry + flags
    const size_t fixed = 393216 + 393216 + 131072 + 131072 + 262144 + 256;
    int Tc = 4;
    for(int cand = 64; cand >= 4; cand >>= 1){
        size_t need = fixed + (size_t)cand*(393216 /*gi*/ + 2*131072 /*emb(=ah=ch), y*/);
        if(need <= ws_size){ Tc = cand; break; }
    }
    const int NC = T_DIM / Tc;

    uint8_t* ws = (uint8_t*)d_ws;
    size_t off = 0;
    u32*  wt_b    = (u32*)(ws + off); off += 393216;   // scan weights, packed f16
    u16*  wiT     = (u16*)(ws + off); off += 393216;   // Wi^T bf16 [768][256]
    u16*  wa1T    = (u16*)(ws + off); off += 131072;   // W_a1^T bf16 [256][256]
    u16*  wc1T    = (u16*)(ws + off); off += 131072;   // W_c1^T bf16 [256][256]
    float* h_carry= (float*)(ws + off); off += 262144;
    int*  flags   = (int*)(ws + off); off += 256;
    u16*  gi_c    = (u16*)(ws + off); off += (size_t)Tc*393216;
    u16*  emb_c   = (u16*)(ws + off); off += (size_t)Tc*131072;  // also ah_c, ch_c
    u16*  y_c     = (u16*)(ws + off); off += (size_t)Tc*131072;
    u16*  ah_c    = emb_c;   // emb dead after gi GEMM
    u16*  ch_c    = emb_c;   // ah dead after actor2

    zero_flags_kernel<<<1, 64, 0, stream>>>(flags);
    detect_kernel<<<64, 256, 0, stream>>>((const unsigned char*)dones, TB, flags);
    cvt_wt_kernel<<<384, 256, 0, stream>>>(Whr, Whz, Whn, wt_b);
    cvt_wT_kernel<<<768, 256, 0, stream>>>(Wi,   wiT,  256, 768);
    cvt_wT_kernel<<<256, 256, 0, stream>>>(W_a1, wa1T, 256, 256);
    cvt_wT_kernel<<<256, 256, 0, stream>>>(W_c1, wc1T, 256, 256);
    hipMemcpyAsync(h_carry, hidden, (size_t)B_DIM*H_DIM*sizeof(float),
                   hipMemcpyDeviceToDevice, stream);

    const int Mc = Tc*B_DIM;          // rows per chunk
    const int gy = Mc/128;

    for(int c = 0; c < NC; ++c){
        const int t0 = c*Tc;
        const float* obs_c = obs + (size_t)t0*B_DIM*OBS_DIM;
        // emb = relu(obs @ W_emb + b_emb)  (f32 A)
        gemm_f32_kernel<<<dim3(2,gy), 256, 0, stream>>>(obs_c, W_emb, b_emb, emb_c, Mc, 256, 128);
        // gi = emb @ Wi + bi  (MFMA)
        gemm_mfma_kernel<0><<<dim3(6,gy), 256, 0, stream>>>(emb_c, wiT, bi, gi_c, Mc, 768, 256);
        // GRU scan chunk: 64 blocks (4 rows each) x 768 threads
        scan_kernel<<<64, 768, 0, stream>>>(gi_c, dones, flags, (const uint4*)wt_b,
                                            bhn, h_carry, y_c, t0, Tc);
        // actor head
        gemm_mfma_kernel<1><<<dim3(2,gy), 256, 0, stream>>>(y_c, wa1T, b_a1, ah_c, Mc, 256, 256);
        actor2_kernel<<<Mc/64, 256, 0, stream>>>(ah_c, W_a2, b_a2,
                                                 avail + (size_t)t0*B_DIM*A_DIM,
                                                 out_logits + (size_t)t0*B_DIM*A_DIM);
        // critic head
        gemm_mfma_kernel<1><<<dim3(2,gy), 256, 0, stream>>>(y_c, wc1T, b_c1, ch_c, Mc, 256, 256);
        critic2_kernel<<<Mc/4, 256, 0, stream>>>(ch_c, W_c2, b_c2, out_value + (size_t)t0*B_DIM);
    }

    hipMemcpyAsync(out_hidden, h_carry, (size_t)B_DIM*H_DIM*sizeof(float),
                   hipMemcpyDeviceToDevice, stream);
}